// Round 1
// baseline (6224.103 us; speedup 1.0000x reference)
//
#include <hip/hip_runtime.h>
#include <math.h>

// ---------------- problem constants ----------------
constexpr int B_  = 2048;
constexpr int S_  = 5;
constexpr int N_  = 80;
constexpr int E_  = 592;
constexpr int FX_ = 8;
constexpr int FF_ = 4;
constexpr int FE_ = 8;
constexpr int D_  = 8;
constexpr int H_  = 800;

constexpr int BS_  = B_ * S_;         // 10240 graphs
constexpr int XD_  = N_ * D_;         // 640
constexpr int ED_  = E_ * D_;         // 4736
constexpr int SEQ_ = XD_ + ED_;       // 5376 (GRU input width)
constexpr int G3_  = 3 * H_;          // 2400
constexpr int MIN_ = S_ * H_;         // 4000 (mlp input width)
constexpr int MH_  = 1280;            // mlp hidden
constexpr int MO_  = S_ * 80;         // 400 (mlp output width)

__device__ __forceinline__ float sigmoidf_(float x) {
    return 1.0f / (1.0f + expf(-x));
}

// ---------------- GNN: one block per (b,s) graph ----------------
__global__ __launch_bounds__(256) void gnn_kernel(
    const float* __restrict__ x,      // [BS, N, FX]
    const int*   __restrict__ ei,     // [BS, 2, E]
    const float* __restrict__ ef,     // [BS, E, FF]
    const float* __restrict__ ea,     // [BS, E, FE]
    const float* __restrict__ Wx,     // [FX, D]
    const float* __restrict__ We,     // [FE, D]
    const float* __restrict__ Wf,     // [FF, D]
    const float* __restrict__ Wedge,  // [2D+FE=24, D]
    float* __restrict__ seq)          // [BS, SEQ]
{
    const int g   = blockIdx.x;
    const int tid = threadIdx.x;

    __shared__ float sWx[FX_ * D_];      // 64
    __shared__ float sWe[FE_ * D_];      // 64
    __shared__ float sWf[FF_ * D_];      // 32
    __shared__ float sWedge[24 * D_];    // 192
    __shared__ float agg[N_ * D_];       // 640
    __shared__ float xout[N_ * D_];      // 640
    __shared__ int   s_src[E_];
    __shared__ int   s_dst[E_];
    __shared__ int   s_min;

    if (tid == 0) s_min = 0x7fffffff;
    if (tid < FX_ * D_) sWx[tid] = Wx[tid];
    if (tid < FE_ * D_) sWe[tid] = We[tid];
    if (tid < FF_ * D_) sWf[tid] = Wf[tid];
    if (tid < 24 * D_)  sWedge[tid] = Wedge[tid];
    for (int i = tid; i < N_ * D_; i += 256) agg[i] = 0.0f;
    __syncthreads();

    // load edges + min over src row (reference: min of edge_index[:,:,0,:])
    const int* srcp = ei + (size_t)g * 2 * E_;
    const int* dstp = srcp + E_;
    int lmin = 0x7fffffff;
    for (int e = tid; e < E_; e += 256) {
        int sv = srcp[e];
        int dv = dstp[e];
        s_src[e] = sv;
        s_dst[e] = dv;
        lmin = min(lmin, sv);
    }
    atomicMin(&s_min, lmin);
    __syncthreads();
    const int mn = s_min;

    // edge messages + scatter-add to nodes
    const float* eag = ea + (size_t)g * E_ * FE_;
    const float* efg = ef + (size_t)g * E_ * FF_;
    for (int e = tid; e < E_; e += 256) {
        float a[FE_], f[FF_];
        const float4* ap = (const float4*)(eag + (size_t)e * FE_);
        float4 a0 = ap[0], a1 = ap[1];
        a[0]=a0.x; a[1]=a0.y; a[2]=a0.z; a[3]=a0.w;
        a[4]=a1.x; a[5]=a1.y; a[6]=a1.z; a[7]=a1.w;
        float4 f0 = *(const float4*)(efg + (size_t)e * FF_);
        f[0]=f0.x; f[1]=f0.y; f[2]=f0.z; f[3]=f0.w;

        int dadj = s_dst[e] - mn;
        if (dadj < 0) dadj += N_;   // NumPy negative-index wrap

        #pragma unroll
        for (int d = 0; d < D_; d++) {
            float m = 0.0f;
            #pragma unroll
            for (int k = 0; k < FE_; k++) m += a[k] * sWe[k * D_ + d];
            #pragma unroll
            for (int k = 0; k < FF_; k++) m += f[k] * sWf[k * D_ + d];
            m = fmaxf(m, 0.0f);
            atomicAdd(&agg[dadj * D_ + d], m);
        }
    }
    __syncthreads();

    // node update: x_out = x + relu(x@Wx + agg)
    const float* xg = x + (size_t)g * N_ * FX_;
    float* seqrow = seq + (size_t)g * SEQ_;
    for (int n = tid; n < N_; n += 256) {
        float xi[FX_];
        const float4* xp = (const float4*)(xg + (size_t)n * FX_);
        float4 x0 = xp[0], x1 = xp[1];
        xi[0]=x0.x; xi[1]=x0.y; xi[2]=x0.z; xi[3]=x0.w;
        xi[4]=x1.x; xi[5]=x1.y; xi[6]=x1.z; xi[7]=x1.w;
        #pragma unroll
        for (int d = 0; d < D_; d++) {
            float v = agg[n * D_ + d];
            #pragma unroll
            for (int k = 0; k < FX_; k++) v += xi[k] * sWx[k * D_ + d];
            v = fmaxf(v, 0.0f);
            float o = xi[d] + v;
            xout[n * D_ + d] = o;
            seqrow[n * D_ + d] = o;
        }
    }
    __syncthreads();

    // edge update: e_out = ea + relu([x_out[src], x_out[dst], ea] @ Wedge)
    for (int e = tid; e < E_; e += 256) {
        int sadj = s_src[e] - mn;                    // >= 0 always
        int dadj = s_dst[e] - mn;
        if (dadj < 0) dadj += N_;
        float a[FE_];
        const float4* ap = (const float4*)(eag + (size_t)e * FE_);
        float4 a0 = ap[0], a1 = ap[1];
        a[0]=a0.x; a[1]=a0.y; a[2]=a0.z; a[3]=a0.w;
        a[4]=a1.x; a[5]=a1.y; a[6]=a1.z; a[7]=a1.w;
        const float* xs = &xout[sadj * D_];
        const float* xd = &xout[dadj * D_];
        #pragma unroll
        for (int d = 0; d < D_; d++) {
            float v = 0.0f;
            #pragma unroll
            for (int k = 0; k < D_; k++)  v += xs[k] * sWedge[k * D_ + d];
            #pragma unroll
            for (int k = 0; k < D_; k++)  v += xd[k] * sWedge[(D_ + k) * D_ + d];
            #pragma unroll
            for (int k = 0; k < FE_; k++) v += a[k] * sWedge[(2 * D_ + k) * D_ + d];
            v = fmaxf(v, 0.0f);
            seqrow[XD_ + e * D_ + d] = a[d] + v;
        }
    }
}

// ---------------- generic fp32 tiled GEMM ----------------
// C[M,Nn] = A[M,K] @ (BT ? Bm[Nn,K]^T : Bm[K,Nn]) + bias[Nn]
// Requirements: M % 128 == 0, K % 8 == 0, Nn % 4 == 0.
template <bool BT>
__global__ __launch_bounds__(256) void sgemm_kernel(
    const float* __restrict__ A,
    const float* __restrict__ Bm,
    const float* __restrict__ bias,
    float* __restrict__ C,
    int M, int Nn, int K)
{
    constexpr int BM = 128, BN = 128, BK = 8;
    __shared__ float As[BK][BM];
    __shared__ float Bs[BK][BN];

    const int tid = threadIdx.x;
    const int m0 = blockIdx.y * BM;
    const int n0 = blockIdx.x * BN;
    const int tx = tid & 15;   // N direction
    const int ty = tid >> 4;   // M direction

    const int arow = tid >> 1;           // 0..127
    const int akq  = (tid & 1) * 4;      // 0 or 4
    const int bkr  = tid >> 5;           // 0..7   (BN layout)
    const int bnq  = (tid & 31) * 4;     // 0..124 (BN layout)

    float acc[8][8] = {};

    for (int k0 = 0; k0 < K; k0 += BK) {
        // stage A tile (transposed into LDS)
        float4 av = *(const float4*)(A + (size_t)(m0 + arow) * K + k0 + akq);
        As[akq + 0][arow] = av.x;
        As[akq + 1][arow] = av.y;
        As[akq + 2][arow] = av.z;
        As[akq + 3][arow] = av.w;

        if (BT) {
            int n = n0 + arow;
            float4 bv = make_float4(0.f, 0.f, 0.f, 0.f);
            if (n < Nn) bv = *(const float4*)(Bm + (size_t)n * K + k0 + akq);
            Bs[akq + 0][arow] = bv.x;
            Bs[akq + 1][arow] = bv.y;
            Bs[akq + 2][arow] = bv.z;
            Bs[akq + 3][arow] = bv.w;
        } else {
            int n = n0 + bnq;
            float4 bv = make_float4(0.f, 0.f, 0.f, 0.f);
            if (n < Nn) bv = *(const float4*)(Bm + (size_t)(k0 + bkr) * Nn + n);
            *(float4*)&Bs[bkr][bnq] = bv;
        }
        __syncthreads();

        #pragma unroll
        for (int kk = 0; kk < BK; kk++) {
            float a[8], b[8];
            *(float4*)&a[0] = *(const float4*)&As[kk][ty * 8];
            *(float4*)&a[4] = *(const float4*)&As[kk][ty * 8 + 4];
            *(float4*)&b[0] = *(const float4*)&Bs[kk][tx * 8];
            *(float4*)&b[4] = *(const float4*)&Bs[kk][tx * 8 + 4];
            #pragma unroll
            for (int i = 0; i < 8; i++)
                #pragma unroll
                for (int j = 0; j < 8; j++)
                    acc[i][j] += a[i] * b[j];
        }
        __syncthreads();
    }

    #pragma unroll
    for (int i = 0; i < 8; i++) {
        int m = m0 + ty * 8 + i;
        float* Crow = C + (size_t)m * Nn;
        #pragma unroll
        for (int j = 0; j < 8; j++) {
            int n = n0 + tx * 8 + j;
            if (n < Nn) Crow[n] = acc[i][j] + (bias ? bias[n] : 0.0f);
        }
    }
}

// ---------------- GRU gate elementwise ----------------
__global__ __launch_bounds__(256) void gru_gates_kernel(
    const float* __restrict__ gi,   // [BS, 3H], row (b*S + t)
    const float* __restrict__ gh,   // [B, 3H]
    float* __restrict__ h,          // [B, H], updated in place
    float* __restrict__ y,          // [B, S*H]
    int t)
{
    int i = blockIdx.x * blockDim.x + threadIdx.x;
    if (i >= B_ * H_) return;
    int b = i / H_;
    int j = i - b * H_;
    const float* girow = gi + ((size_t)b * S_ + t) * G3_;
    const float* ghrow = gh + (size_t)b * G3_;
    float r = sigmoidf_(girow[j] + ghrow[j]);
    float z = sigmoidf_(girow[H_ + j] + ghrow[H_ + j]);
    float n = tanhf(girow[2 * H_ + j] + r * ghrow[2 * H_ + j]);
    float hp = h[i];
    float hn = (1.0f - z) * n + z * hp;
    h[i] = hn;
    y[(size_t)b * MIN_ + t * H_ + j] = hn;
}

// ---------------- launch ----------------
extern "C" void kernel_launch(void* const* d_in, const int* in_sizes, int n_in,
                              void* d_out, int out_size, void* d_ws, size_t ws_size,
                              hipStream_t stream) {
    const float* x     = (const float*)d_in[0];
    const int*   ei    = (const int*)  d_in[1];
    const float* ef    = (const float*)d_in[2];
    const float* ea    = (const float*)d_in[3];
    const float* Wx    = (const float*)d_in[4];
    const float* We    = (const float*)d_in[5];
    const float* Wf    = (const float*)d_in[6];
    const float* Wedge = (const float*)d_in[7];
    const float* w_ih  = (const float*)d_in[8];
    const float* w_hh  = (const float*)d_in[9];
    const float* b_ih  = (const float*)d_in[10];
    const float* b_hh  = (const float*)d_in[11];
    const float* w1    = (const float*)d_in[12];
    const float* b1    = (const float*)d_in[13];
    const float* w2    = (const float*)d_in[14];
    const float* b2    = (const float*)d_in[15];
    float* out = (float*)d_out;

    float* ws  = (float*)d_ws;
    float* seq = ws;                              // [BS, SEQ]   55,050,240
    float* gi  = seq + (size_t)BS_ * SEQ_;        // [BS, 3H]    24,576,000
    float* gh  = gi  + (size_t)BS_ * G3_;         // [B, 3H]      4,915,200
    float* h   = gh  + (size_t)B_ * G3_;          // [B, H]       1,638,400
    float* y   = h   + (size_t)B_ * H_;           // [B, S*H]     8,192,000
    float* t1  = y   + (size_t)B_ * MIN_;         // [B, MH]      2,621,440

    // h0 = 0
    hipMemsetAsync(h, 0, (size_t)B_ * H_ * sizeof(float), stream);

    // GNN over all graphs -> seq
    gnn_kernel<<<BS_, 256, 0, stream>>>(x, ei, ef, ea, Wx, We, Wf, Wedge, seq);

    // gi = seq @ w_ih^T + b_ih  (all timesteps at once; time-independent)
    {
        dim3 grid((G3_ + 127) / 128, BS_ / 128);
        sgemm_kernel<true><<<grid, 256, 0, stream>>>(seq, w_ih, b_ih, gi, BS_, G3_, SEQ_);
    }

    // GRU steps (sequential in t): gh = h @ w_hh^T + b_hh, then gates
    for (int t = 0; t < S_; t++) {
        dim3 grid((G3_ + 127) / 128, B_ / 128);
        sgemm_kernel<true><<<grid, 256, 0, stream>>>(h, w_hh, b_hh, gh, B_, G3_, H_);
        gru_gates_kernel<<<(B_ * H_ + 255) / 256, 256, 0, stream>>>(gi, gh, h, y, t);
    }

    // MLP: t1 = y @ w1 + b1 ; out = t1 @ w2 + b2
    {
        dim3 grid((MH_ + 127) / 128, B_ / 128);
        sgemm_kernel<false><<<grid, 256, 0, stream>>>(y, w1, b1, t1, B_, MH_, MIN_);
    }
    {
        dim3 grid((MO_ + 127) / 128, B_ / 128);
        sgemm_kernel<false><<<grid, 256, 0, stream>>>(t1, w2, b2, out, B_, MO_, MH_);
    }
}

// Round 2
// 1554.288 us; speedup vs baseline: 4.0045x; 4.0045x over previous
//
#include <hip/hip_runtime.h>
#include <math.h>

// ---------------- problem constants ----------------
constexpr int B_  = 2048;
constexpr int S_  = 5;
constexpr int N_  = 80;
constexpr int E_  = 592;
constexpr int FX_ = 8;
constexpr int FF_ = 4;
constexpr int FE_ = 8;
constexpr int D_  = 8;
constexpr int H_  = 800;

constexpr int BS_  = B_ * S_;         // 10240 graphs
constexpr int XD_  = N_ * D_;         // 640
constexpr int ED_  = E_ * D_;         // 4736
constexpr int SEQ_ = XD_ + ED_;       // 5376 (GRU input width)
constexpr int G3_  = 3 * H_;          // 2400
constexpr int MIN_ = S_ * H_;         // 4000 (mlp input width)
constexpr int MH_  = 1280;            // mlp hidden
constexpr int MO_  = S_ * 80;         // 400 (mlp output width)

typedef __bf16 bf16_t;
typedef __bf16 bf16x8 __attribute__((ext_vector_type(8)));
typedef float  f32x4  __attribute__((ext_vector_type(4)));

__device__ __forceinline__ float sigmoidf_(float x) {
    return 1.0f / (1.0f + expf(-x));
}

// async global->LDS, 16 bytes per lane (global_load_lds_dwordx4)
__device__ __forceinline__ void async16(const void* g, void* l) {
    __builtin_amdgcn_global_load_lds(
        (const __attribute__((address_space(1))) unsigned int*)g,
        (__attribute__((address_space(3))) unsigned int*)l,
        16, 0, 0);
}

// ---------------- GNN: one block per (b,s) graph ----------------
__global__ __launch_bounds__(256) void gnn_kernel(
    const float* __restrict__ x,      // [BS, N, FX]
    const int*   __restrict__ ei,     // [BS, 2, E]
    const float* __restrict__ ef,     // [BS, E, FF]
    const float* __restrict__ ea,     // [BS, E, FE]
    const float* __restrict__ Wx,     // [FX, D]
    const float* __restrict__ We,     // [FE, D]
    const float* __restrict__ Wf,     // [FF, D]
    const float* __restrict__ Wedge,  // [2D+FE=24, D]
    bf16_t* __restrict__ seq)         // [BS, SEQ] bf16
{
    const int g   = blockIdx.x;
    const int tid = threadIdx.x;

    __shared__ float sWx[FX_ * D_];
    __shared__ float sWe[FE_ * D_];
    __shared__ float sWf[FF_ * D_];
    __shared__ float sWedge[24 * D_];
    __shared__ float agg[N_ * D_];
    __shared__ float xout[N_ * D_];
    __shared__ int   s_src[E_];
    __shared__ int   s_dst[E_];
    __shared__ int   s_min;

    if (tid == 0) s_min = 0x7fffffff;
    if (tid < FX_ * D_) sWx[tid] = Wx[tid];
    if (tid < FE_ * D_) sWe[tid] = We[tid];
    if (tid < FF_ * D_) sWf[tid] = Wf[tid];
    if (tid < 24 * D_)  sWedge[tid] = Wedge[tid];
    for (int i = tid; i < N_ * D_; i += 256) agg[i] = 0.0f;
    __syncthreads();

    const int* srcp = ei + (size_t)g * 2 * E_;
    const int* dstp = srcp + E_;
    int lmin = 0x7fffffff;
    for (int e = tid; e < E_; e += 256) {
        int sv = srcp[e];
        int dv = dstp[e];
        s_src[e] = sv;
        s_dst[e] = dv;
        lmin = min(lmin, sv);
    }
    atomicMin(&s_min, lmin);
    __syncthreads();
    const int mn = s_min;

    const float* eag = ea + (size_t)g * E_ * FE_;
    const float* efg = ef + (size_t)g * E_ * FF_;
    for (int e = tid; e < E_; e += 256) {
        float a[FE_], f[FF_];
        const float4* ap = (const float4*)(eag + (size_t)e * FE_);
        float4 a0 = ap[0], a1 = ap[1];
        a[0]=a0.x; a[1]=a0.y; a[2]=a0.z; a[3]=a0.w;
        a[4]=a1.x; a[5]=a1.y; a[6]=a1.z; a[7]=a1.w;
        float4 f0 = *(const float4*)(efg + (size_t)e * FF_);
        f[0]=f0.x; f[1]=f0.y; f[2]=f0.z; f[3]=f0.w;

        int dadj = s_dst[e] - mn;
        if (dadj < 0) dadj += N_;   // NumPy negative-index wrap

        #pragma unroll
        for (int d = 0; d < D_; d++) {
            float m = 0.0f;
            #pragma unroll
            for (int k = 0; k < FE_; k++) m += a[k] * sWe[k * D_ + d];
            #pragma unroll
            for (int k = 0; k < FF_; k++) m += f[k] * sWf[k * D_ + d];
            m = fmaxf(m, 0.0f);
            atomicAdd(&agg[dadj * D_ + d], m);
        }
    }
    __syncthreads();

    const float* xg = x + (size_t)g * N_ * FX_;
    bf16_t* seqrow = seq + (size_t)g * SEQ_;
    for (int n = tid; n < N_; n += 256) {
        float xi[FX_];
        const float4* xp = (const float4*)(xg + (size_t)n * FX_);
        float4 x0 = xp[0], x1 = xp[1];
        xi[0]=x0.x; xi[1]=x0.y; xi[2]=x0.z; xi[3]=x0.w;
        xi[4]=x1.x; xi[5]=x1.y; xi[6]=x1.z; xi[7]=x1.w;
        #pragma unroll
        for (int d = 0; d < D_; d++) {
            float v = agg[n * D_ + d];
            #pragma unroll
            for (int k = 0; k < FX_; k++) v += xi[k] * sWx[k * D_ + d];
            v = fmaxf(v, 0.0f);
            float o = xi[d] + v;
            xout[n * D_ + d] = o;
            seqrow[n * D_ + d] = (bf16_t)o;
        }
    }
    __syncthreads();

    for (int e = tid; e < E_; e += 256) {
        int sadj = s_src[e] - mn;
        int dadj = s_dst[e] - mn;
        if (dadj < 0) dadj += N_;
        float a[FE_];
        const float4* ap = (const float4*)(eag + (size_t)e * FE_);
        float4 a0 = ap[0], a1 = ap[1];
        a[0]=a0.x; a[1]=a0.y; a[2]=a0.z; a[3]=a0.w;
        a[4]=a1.x; a[5]=a1.y; a[6]=a1.z; a[7]=a1.w;
        const float* xs = &xout[sadj * D_];
        const float* xd = &xout[dadj * D_];
        #pragma unroll
        for (int d = 0; d < D_; d++) {
            float v = 0.0f;
            #pragma unroll
            for (int k = 0; k < D_; k++)  v += xs[k] * sWedge[k * D_ + d];
            #pragma unroll
            for (int k = 0; k < D_; k++)  v += xd[k] * sWedge[(D_ + k) * D_ + d];
            #pragma unroll
            for (int k = 0; k < FE_; k++) v += a[k] * sWedge[(2 * D_ + k) * D_ + d];
            v = fmaxf(v, 0.0f);
            seqrow[XD_ + e * D_ + d] = (bf16_t)(a[d] + v);
        }
    }
}

// ---------------- bf16 MFMA GEMM (m97 structure) ----------------
// C[M,Nn] = A[M,K]_bf16 @ Bm[Nn,K]_bf16^T + bias[Nn]
// Tile 128x128, BK=32, 4 waves (2x2 of 64x64), 16x16x32 MFMA.
// Requires: M % 128 == 0, K % 32 == 0. Nn handled by clamp+mask.
template <typename OutT>
__global__ __launch_bounds__(256) void mfma_gemm_bt(
    const bf16_t* __restrict__ A,
    const bf16_t* __restrict__ Bm,
    const float*  __restrict__ bias,
    OutT* __restrict__ C,
    int M, int Nn, int K)
{
    __shared__ bf16_t As[128 * 32];
    __shared__ bf16_t Bs[128 * 32];

    const int tid  = threadIdx.x;
    const int wave = tid >> 6;
    const int lane = tid & 63;
    const int m0 = blockIdx.y * 128;
    const int n0 = blockIdx.x * 128;
    const int wm = (wave & 1) * 64;
    const int wn = (wave >> 1) * 64;

    // staging: each thread moves 16B; one issue = 64 rows x 32 k
    const int srow  = tid >> 2;        // 0..63
    const int skoff = (tid & 3) * 8;   // 0,8,16,24

    // fragment addressing (16x16x32): elem [fm][fk + j]
    const int fm = lane & 15;
    const int fk = (lane >> 4) * 8;

    f32x4 acc[4][4] = {};

    const bf16_t* a_ptr0 = A + (size_t)(m0 + srow) * K + skoff;
    const bf16_t* a_ptr1 = a_ptr0 + (size_t)64 * K;
    int brow0 = n0 + srow;      if (brow0 > Nn - 1) brow0 = Nn - 1;
    int brow1 = n0 + 64 + srow; if (brow1 > Nn - 1) brow1 = Nn - 1;
    const bf16_t* b_ptr0 = Bm + (size_t)brow0 * K + skoff;
    const bf16_t* b_ptr1 = Bm + (size_t)brow1 * K + skoff;

    bf16_t* lA0 = &As[srow * 32 + skoff];
    bf16_t* lA1 = &As[(64 + srow) * 32 + skoff];
    bf16_t* lB0 = &Bs[srow * 32 + skoff];
    bf16_t* lB1 = &Bs[(64 + srow) * 32 + skoff];

    for (int k0 = 0; k0 < K; k0 += 32) {
        async16(a_ptr0 + k0, lA0);
        async16(a_ptr1 + k0, lA1);
        async16(b_ptr0 + k0, lB0);
        async16(b_ptr1 + k0, lB1);
        __syncthreads();   // drains vmcnt: tiles staged

        bf16x8 af[4], bfm[4];
        #pragma unroll
        for (int i = 0; i < 4; i++)
            af[i] = *(const bf16x8*)&As[(wm + i * 16 + fm) * 32 + fk];
        #pragma unroll
        for (int j = 0; j < 4; j++)
            bfm[j] = *(const bf16x8*)&Bs[(wn + j * 16 + fm) * 32 + fk];

        #pragma unroll
        for (int i = 0; i < 4; i++)
            #pragma unroll
            for (int j = 0; j < 4; j++)
                acc[i][j] = __builtin_amdgcn_mfma_f32_16x16x32_bf16(
                    af[i], bfm[j], acc[i][j], 0, 0, 0);

        __syncthreads();   // all reads done before next overwrite
    }

    // C/D layout: col = lane&15, row = (lane>>4)*4 + reg  [m89/m91]
    const int crow = (lane >> 4) * 4;
    const int ccol = lane & 15;
    #pragma unroll
    for (int i = 0; i < 4; i++) {
        #pragma unroll
        for (int j = 0; j < 4; j++) {
            int row = m0 + wm + i * 16 + crow;
            int col = n0 + wn + j * 16 + ccol;
            if (col < Nn) {
                float bv = bias[col];
                #pragma unroll
                for (int r = 0; r < 4; r++) {
                    float v = acc[i][j][r] + bv;
                    C[(size_t)(row + r) * Nn + col] = (OutT)v;
                }
            }
        }
    }
}

// ---------------- fp32 -> bf16 flat convert ----------------
__global__ __launch_bounds__(256) void f2bf_kernel(
    const float* __restrict__ in, bf16_t* __restrict__ out, int n)
{
    int i = (blockIdx.x * 256 + threadIdx.x) * 4;
    if (i + 3 < n) {
        float4 v = *(const float4*)&in[i];
        out[i + 0] = (bf16_t)v.x;
        out[i + 1] = (bf16_t)v.y;
        out[i + 2] = (bf16_t)v.z;
        out[i + 3] = (bf16_t)v.w;
    } else {
        for (; i < n; i++) out[i] = (bf16_t)in[i];
    }
}

// ---------------- fp32 [K,N] -> bf16 [N,K] transpose-convert ----------------
__global__ __launch_bounds__(256) void tconv_kernel(
    const float* __restrict__ in, bf16_t* __restrict__ out, int K, int N)
{
    __shared__ float tile[32][33];
    int k0 = blockIdx.y * 32, n0 = blockIdx.x * 32;
    int tx = threadIdx.x & 31, ty = threadIdx.x >> 5;  // 32x8
    #pragma unroll
    for (int r = 0; r < 32; r += 8) {
        int k = k0 + ty + r, n = n0 + tx;
        tile[ty + r][tx] = (k < K && n < N) ? in[(size_t)k * N + n] : 0.0f;
    }
    __syncthreads();
    #pragma unroll
    for (int r = 0; r < 32; r += 8) {
        int n = n0 + ty + r, k = k0 + tx;
        if (n < N && k < K) out[(size_t)n * K + k] = (bf16_t)tile[tx][ty + r];
    }
}

// ---------------- GRU gate elementwise ----------------
__global__ __launch_bounds__(256) void gru_gates_kernel(
    const float* __restrict__ gi,   // [BS, 3H], row (b*S + t)
    const float* __restrict__ gh,   // [B, 3H]
    float*  __restrict__ h,         // [B, H] fp32 recurrence state
    bf16_t* __restrict__ hb,        // [B, H] bf16 copy (next-step GEMM A)
    bf16_t* __restrict__ yb,        // [B, S*H] bf16 (MLP GEMM A)
    int t)
{
    int i = blockIdx.x * blockDim.x + threadIdx.x;
    if (i >= B_ * H_) return;
    int b = i / H_;
    int j = i - b * H_;
    const float* girow = gi + ((size_t)b * S_ + t) * G3_;
    const float* ghrow = gh + (size_t)b * G3_;
    float r = sigmoidf_(girow[j] + ghrow[j]);
    float z = sigmoidf_(girow[H_ + j] + ghrow[H_ + j]);
    float n = tanhf(girow[2 * H_ + j] + r * ghrow[2 * H_ + j]);
    float hp = h[i];
    float hn = (1.0f - z) * n + z * hp;
    h[i] = hn;
    hb[i] = (bf16_t)hn;
    yb[(size_t)b * MIN_ + t * H_ + j] = (bf16_t)hn;
}

// ---------------- launch ----------------
extern "C" void kernel_launch(void* const* d_in, const int* in_sizes, int n_in,
                              void* d_out, int out_size, void* d_ws, size_t ws_size,
                              hipStream_t stream) {
    const float* x     = (const float*)d_in[0];
    const int*   ei    = (const int*)  d_in[1];
    const float* ef    = (const float*)d_in[2];
    const float* ea    = (const float*)d_in[3];
    const float* Wx    = (const float*)d_in[4];
    const float* We    = (const float*)d_in[5];
    const float* Wf    = (const float*)d_in[6];
    const float* Wedge = (const float*)d_in[7];
    const float* w_ih  = (const float*)d_in[8];
    const float* w_hh  = (const float*)d_in[9];
    const float* b_ih  = (const float*)d_in[10];
    const float* b_hh  = (const float*)d_in[11];
    const float* w1    = (const float*)d_in[12];
    const float* b1    = (const float*)d_in[13];
    const float* w2    = (const float*)d_in[14];
    const float* b2    = (const float*)d_in[15];
    float* out = (float*)d_out;

    // ---- workspace carve-up (bytes, 256-aligned) ----
    char* p = (char*)d_ws;
    auto alloc = [&](size_t bytes) {
        void* r = (void*)p;
        p += (bytes + 255) & ~(size_t)255;
        return r;
    };
    bf16_t* seq   = (bf16_t*)alloc((size_t)BS_ * SEQ_ * 2);   // 110.1 MB
    bf16_t* wihb  = (bf16_t*)alloc((size_t)G3_ * SEQ_ * 2);   //  25.8 MB
    bf16_t* whhb  = (bf16_t*)alloc((size_t)G3_ * H_ * 2);     //   3.8 MB
    bf16_t* w1t   = (bf16_t*)alloc((size_t)MH_ * MIN_ * 2);   //  10.2 MB
    bf16_t* w2t   = (bf16_t*)alloc((size_t)MO_ * MH_ * 2);    //   1.0 MB
    float*  gi    = (float*) alloc((size_t)BS_ * G3_ * 4);    //  98.3 MB
    float*  gh    = (float*) alloc((size_t)B_ * G3_ * 4);     //  19.7 MB
    float*  h     = (float*) alloc((size_t)B_ * H_ * 4);      //   6.6 MB
    bf16_t* hb    = (bf16_t*)alloc((size_t)B_ * H_ * 2);      //   3.3 MB
    bf16_t* yb    = (bf16_t*)alloc((size_t)B_ * MIN_ * 2);    //  16.4 MB
    bf16_t* t1b   = (bf16_t*)alloc((size_t)B_ * MH_ * 2);     //   5.2 MB

    // h0 = 0 (fp32 and bf16 views)
    hipMemsetAsync(h,  0, (size_t)B_ * H_ * sizeof(float), stream);
    hipMemsetAsync(hb, 0, (size_t)B_ * H_ * sizeof(bf16_t), stream);

    // weight converts
    {
        int n = G3_ * SEQ_;
        f2bf_kernel<<<(n / 4 + 255) / 256, 256, 0, stream>>>(w_ih, wihb, n);
    }
    {
        int n = G3_ * H_;
        f2bf_kernel<<<(n / 4 + 255) / 256, 256, 0, stream>>>(w_hh, whhb, n);
    }
    {   // w1 [MIN, MH] -> w1t [MH, MIN]
        dim3 grid((MH_ + 31) / 32, (MIN_ + 31) / 32);
        tconv_kernel<<<grid, 256, 0, stream>>>(w1, w1t, MIN_, MH_);
    }
    {   // w2 [MH, MO] -> w2t [MO, MH]
        dim3 grid((MO_ + 31) / 32, (MH_ + 31) / 32);
        tconv_kernel<<<grid, 256, 0, stream>>>(w2, w2t, MH_, MO_);
    }

    // GNN over all graphs -> seq (bf16)
    gnn_kernel<<<BS_, 256, 0, stream>>>(x, ei, ef, ea, Wx, We, Wf, Wedge, seq);

    // gi = seq @ w_ih^T + b_ih  (all timesteps at once)
    {
        dim3 grid((G3_ + 127) / 128, BS_ / 128);   // 19 x 80
        mfma_gemm_bt<float><<<grid, 256, 0, stream>>>(seq, wihb, b_ih, gi, BS_, G3_, SEQ_);
    }

    // GRU steps: gh = h @ w_hh^T + b_hh, then fused gates
    for (int t = 0; t < S_; t++) {
        dim3 grid((G3_ + 127) / 128, B_ / 128);    // 19 x 16
        mfma_gemm_bt<float><<<grid, 256, 0, stream>>>(hb, whhb, b_hh, gh, B_, G3_, H_);
        gru_gates_kernel<<<(B_ * H_ + 255) / 256, 256, 0, stream>>>(gi, gh, h, hb, yb, t);
    }

    // MLP: t1 = y @ w1 + b1 (bf16 out) ; out = t1 @ w2 + b2 (fp32 out)
    {
        dim3 grid((MH_ + 127) / 128, B_ / 128);    // 10 x 16
        mfma_gemm_bt<bf16_t><<<grid, 256, 0, stream>>>(yb, w1t, b1, t1b, B_, MH_, MIN_);
    }
    {
        dim3 grid((MO_ + 127) / 128, B_ / 128);    // 4 x 16
        mfma_gemm_bt<float><<<grid, 256, 0, stream>>>(t1b, w2t, b2, out, B_, MO_, MH_);
    }
}